// Round 7
// baseline (194.187 us; speedup 1.0000x reference)
//
#include <hip/hip_runtime.h>
#include <hip/hip_bf16.h>
#include <cstdint>
#include <cstddef>

// B=8, T=2048, D=128 causal dual-mode attention.
// logits = Qeff . K^T with Qeff[t][d] = -alpha*scale*q[t][d] + (1-alpha)*scale*q[t][(d+1)%D]
// (feature-roll moved from K onto Q), then causal softmax, then @V.
//
// R7 = R6 structure with fixed partial-slot accounting:
//   POSLOTS_PER_B = 346 (was 344: cross-batch aliasing + 128KB stomp of ml).
//   ml compacted: slot = b*410 + pofs + c + s  (sum nsl = pofs + c).
// Wave job = (batch, 32-row q-chunk c, segment s); tps=ceil(nt/8); no barriers;
// K/V direct from XCD-pinned L2; seg0 f32 partial lives in out; combine merges.

typedef __attribute__((ext_vector_type(8))) short short8;
typedef __attribute__((ext_vector_type(4))) float f32x4;

#define T_DIM 2048
#define D_DIM 128
#define B_DIM 8
#define POSLOTS_PER_B 346   // sum over c of (nsl(c)-1)  [audited R7]
#define MLSLOTS_PER_B 410   // sum over c of nsl(c) = 346 + 64

__device__ __forceinline__ unsigned short f2bf(float f) {
  unsigned u = __builtin_bit_cast(unsigned, f);
  u += 0x7FFFu + ((u >> 16) & 1u);          // RNE
  return (unsigned short)(u >> 16);
}
__device__ __forceinline__ float bf2f(unsigned short u) {
  return __uint_as_float(((unsigned)u) << 16);
}

// ---------------- prepass: K->bf16, V->bf16 transposed [b][d][s] ----------------
__global__ __launch_bounds__(256) void prep_kv(
    const float* __restrict__ k, const float* __restrict__ v,
    unsigned short* __restrict__ kbf, unsigned short* __restrict__ vt)
{
  __shared__ unsigned short tile[64 * 136];   // V rows as bf16, pitch 136
  const int b = blockIdx.x, s0 = blockIdx.y * 64;
  const int tid = threadIdx.x;
#pragma unroll
  for (int u = 0; u < 4; ++u) {
    int c = u * 256 + tid;                    // 1024 chunks = 64 rows x 16
    int r = c >> 4, c8 = c & 15;
    size_t row = (size_t)b * T_DIM + s0 + r;
    float4 ka = *(const float4*)(k + row * D_DIM + c8 * 8);
    float4 kb2 = *(const float4*)(k + row * D_DIM + c8 * 8 + 4);
    short8 ko = { (short)f2bf(ka.x), (short)f2bf(ka.y), (short)f2bf(ka.z), (short)f2bf(ka.w),
                  (short)f2bf(kb2.x), (short)f2bf(kb2.y), (short)f2bf(kb2.z), (short)f2bf(kb2.w) };
    *(short8*)(kbf + row * D_DIM + c8 * 8) = ko;
    float4 va = *(const float4*)(v + row * D_DIM + c8 * 8);
    float4 vb2 = *(const float4*)(v + row * D_DIM + c8 * 8 + 4);
    short8 vo = { (short)f2bf(va.x), (short)f2bf(va.y), (short)f2bf(va.z), (short)f2bf(va.w),
                  (short)f2bf(vb2.x), (short)f2bf(vb2.y), (short)f2bf(vb2.z), (short)f2bf(vb2.w) };
    *(short8*)(tile + r * 136 + c8 * 8) = vo;
  }
  __syncthreads();
#pragma unroll
  for (int u = 0; u < 8; ++u) {
    int c = u * 256 + tid;                    // 2048 = 128 d x 16 s-quads
    int d = c >> 4, sq = c & 15;
    ushort4 o = { tile[(sq * 4 + 0) * 136 + d], tile[(sq * 4 + 1) * 136 + d],
                  tile[(sq * 4 + 2) * 136 + d], tile[(sq * 4 + 3) * 136 + d] };
    *(ushort4*)(vt + ((size_t)b * D_DIM + d) * T_DIM + s0 + sq * 4) = o;
  }
}

// ---------------- main: wave-granular split-KV, no barriers ----------------
__global__ __launch_bounds__(256, 4) void attn_kernel(
    const float* __restrict__ q, const unsigned short* __restrict__ kbf,
    const unsigned short* __restrict__ vt, const float* __restrict__ modep,
    float* __restrict__ out, unsigned short* __restrict__ po, float* __restrict__ ml)
{
  __shared__ char psm[4 * 2048];              // per-wave P buffers
  const int tid = threadIdx.x;
  const int w = tid >> 6, lane = tid & 63;
  const int t16 = lane & 15, g = lane >> 4;
  const int b = blockIdx.x;                   // linear%8==b -> batch pinned to XCD
  const int c = blockIdx.y;                   // 32-row q-chunk
  const int s = blockIdx.z * 4 + w;           // segment id 0..7
  const int nt = (c + 2) >> 1;                // causal 64-col tiles
  const int tps = (nt + 7) >> 3;              // tiles per segment
  const int t0 = s * tps;
  if (t0 >= nt) return;                       // dead wave (no barriers -> safe)
  const int t1 = min(nt, t0 + tps);
  const int nsl = (nt + tps - 1) / tps;       // live segments for this chunk
  const int qb = c * 32;

  char* pw = psm + w * 2048;                  // this wave's P [16][128B] swizzled
  const unsigned short* kbase = kbf + (size_t)b * T_DIM * D_DIM;
  const unsigned short* vbase = vt + (size_t)b * D_DIM * T_DIM;

  // ---- Qeff fragments built from f32 q (roll+mix+scale folded) ----
  const float alpha = 1.f / (1.f + __expf(-modep[0]));
  const float scale = 0.08838834764831845f;   // 1/sqrt(128)
  const float ca = -alpha * scale, cb = (1.f - alpha) * scale;
  short8 qf[2][4];
#pragma unroll
  for (int mt = 0; mt < 2; ++mt) {
    const float* qr = q + ((size_t)b * T_DIM + qb + mt * 16 + t16) * D_DIM;
#pragma unroll
    for (int dd = 0; dd < 4; ++dd) {
      int dstart = dd * 32 + g * 8;
      float e[9];
      float4 f0 = *(const float4*)(qr + dstart);
      float4 f1 = *(const float4*)(qr + dstart + 4);
      e[0] = f0.x; e[1] = f0.y; e[2] = f0.z; e[3] = f0.w;
      e[4] = f1.x; e[5] = f1.y; e[6] = f1.z; e[7] = f1.w;
      e[8] = qr[(dstart + 8) & 127];
      short8 qv;
#pragma unroll
      for (int i = 0; i < 8; ++i) qv[i] = (short)f2bf(ca * e[i] + cb * e[i + 1]);
      qf[mt][dd] = qv;
    }
  }

  f32x4 acc[2][8];
#pragma unroll
  for (int mt = 0; mt < 2; ++mt)
#pragma unroll
    for (int dt = 0; dt < 8; ++dt) acc[mt][dt] = (f32x4){0.f, 0.f, 0.f, 0.f};
  float mrun[2][4], lrun[2][4];
#pragma unroll
  for (int mt = 0; mt < 2; ++mt)
#pragma unroll
    for (int r = 0; r < 4; ++r) { mrun[mt][r] = -1e30f; lrun[mt][r] = 0.f; }

  for (int kt = t0; kt < t1; ++kt) {
    const int kv0 = kt * 64;

    // ---- S = Qeff . K^T (K fragments direct from L2) ----
    f32x4 sj[2][4];
#pragma unroll
    for (int jt = 0; jt < 4; ++jt) {
      const unsigned short* kr = kbase + (size_t)(kv0 + jt * 16 + t16) * D_DIM + g * 8;
      f32x4 s0 = (f32x4){0.f, 0.f, 0.f, 0.f};
      f32x4 s1 = (f32x4){0.f, 0.f, 0.f, 0.f};
#pragma unroll
      for (int dd = 0; dd < 4; ++dd) {
        short8 kf = *(const short8*)(kr + dd * 32);
        s0 = __builtin_amdgcn_mfma_f32_16x16x32_bf16(qf[0][dd], kf, s0, 0, 0, 0);
        s1 = __builtin_amdgcn_mfma_f32_16x16x32_bf16(qf[1][dd], kf, s1, 0, 0, 0);
      }
      sj[0][jt] = s0; sj[1][jt] = s1;
    }

    const bool needmask = (kt == nt - 1);
#pragma unroll
    for (int mt = 0; mt < 2; ++mt) {
      if (needmask) {
#pragma unroll
        for (int jt = 0; jt < 4; ++jt) {
          int sg = kv0 + jt * 16 + t16;
#pragma unroll
          for (int r = 0; r < 4; ++r) {
            int tg = qb + mt * 16 + 4 * g + r;
            if (sg > tg) sj[mt][jt][r] = -1e30f;
          }
        }
      }
      // online softmax (row = 4g+r; reduce over 16-lane t16 group)
      float tm[4];
#pragma unroll
      for (int r = 0; r < 4; ++r)
        tm[r] = fmaxf(fmaxf(sj[mt][0][r], sj[mt][1][r]), fmaxf(sj[mt][2][r], sj[mt][3][r]));
#pragma unroll
      for (int r = 0; r < 4; ++r) {
        tm[r] = fmaxf(tm[r], __shfl_xor(tm[r], 1));
        tm[r] = fmaxf(tm[r], __shfl_xor(tm[r], 2));
        tm[r] = fmaxf(tm[r], __shfl_xor(tm[r], 4));
        tm[r] = fmaxf(tm[r], __shfl_xor(tm[r], 8));
      }
      float corr[4], rs[4];
#pragma unroll
      for (int r = 0; r < 4; ++r) {
        float mnew = fmaxf(mrun[mt][r], tm[r]);
        corr[r] = __expf(mrun[mt][r] - mnew);
        mrun[mt][r] = mnew;
        rs[r] = 0.f;
      }
#pragma unroll
      for (int jt = 0; jt < 4; ++jt)
#pragma unroll
        for (int r = 0; r < 4; ++r) {
          float p = __expf(sj[mt][jt][r] - mrun[mt][r]);
          sj[mt][jt][r] = p;
          rs[r] += p;
        }
#pragma unroll
      for (int r = 0; r < 4; ++r) {
        rs[r] += __shfl_xor(rs[r], 1);
        rs[r] += __shfl_xor(rs[r], 2);
        rs[r] += __shfl_xor(rs[r], 4);
        rs[r] += __shfl_xor(rs[r], 8);
        lrun[mt][r] = lrun[mt][r] * corr[r] + rs[r];
      }
#pragma unroll
      for (int dt = 0; dt < 8; ++dt)
#pragma unroll
        for (int r = 0; r < 4; ++r) acc[mt][dt][r] *= corr[r];

      // P -> per-wave LDS (C-layout -> [row][col] swizzled); intra-wave only
#pragma unroll
      for (int jt = 0; jt < 4; ++jt)
#pragma unroll
        for (int r = 0; r < 4; ++r) {
          int rloc = 4 * g + r;
          *(unsigned short*)(pw + rloc * 128 + ((2 * (jt * 16 + t16)) ^ ((rloc & 7) << 4))) =
              f2bf(sj[mt][jt][r]);
        }

      // ---- O[mt] += P . V (V fragments direct from L2) ----
#pragma unroll
      for (int k0 = 0; k0 < 2; ++k0) {
        short8 pf = *(const short8*)(pw + t16 * 128 + ((k0 * 64 + g * 16) ^ ((t16 & 7) << 4)));
#pragma unroll
        for (int dt = 0; dt < 8; ++dt) {
          const unsigned short* vr = vbase + (size_t)(dt * 16 + t16) * T_DIM + kv0 + k0 * 32 + g * 8;
          short8 vf = *(const short8*)vr;
          acc[mt][dt] = __builtin_amdgcn_mfma_f32_16x16x32_bf16(pf, vf, acc[mt][dt], 0, 0, 0);
        }
      }
    }
  }

  // ---- epilogue ----
  if (nsl == 1) {
    // only chunk c=0,1: single segment, write normalized
#pragma unroll
    for (int mt = 0; mt < 2; ++mt)
#pragma unroll
      for (int r = 0; r < 4; ++r) {
        float inv = 1.0f / lrun[mt][r];
#pragma unroll
        for (int dt = 0; dt < 8; ++dt)
          out[((size_t)b * T_DIM + qb + mt * 16 + 4 * g + r) * D_DIM + dt * 16 + t16] =
              acc[mt][dt][r] * inv;
      }
  } else {
    // compact prefix: pofs = sum over cc<c of (nsl(cc)-1); sum of nsl = pofs + c
    int pofs = 0;
    for (int cc = 0; cc < c; ++cc) {
      int ntc = (cc + 2) >> 1, tpsc = (ntc + 7) >> 3;
      pofs += (ntc + tpsc - 1) / tpsc - 1;
    }
    if (s == 0) {
      // seg0 partial lives (unnormalized, f32) in out[]
#pragma unroll
      for (int mt = 0; mt < 2; ++mt)
#pragma unroll
        for (int r = 0; r < 4; ++r)
#pragma unroll
          for (int dt = 0; dt < 8; ++dt)
            out[((size_t)b * T_DIM + qb + mt * 16 + 4 * g + r) * D_DIM + dt * 16 + t16] =
                acc[mt][dt][r];
    } else {
      unsigned short* pob = po + ((size_t)b * POSLOTS_PER_B + pofs + (s - 1)) * 4096;
#pragma unroll
      for (int mt = 0; mt < 2; ++mt)
#pragma unroll
        for (int r = 0; r < 4; ++r) {
          int rb = mt * 16 + 4 * g + r;
#pragma unroll
          for (int dt = 0; dt < 8; ++dt)
            pob[rb * 128 + dt * 16 + t16] = f2bf(acc[mt][dt][r]);
        }
    }
    if (t16 == 0) {
      const size_t mlslot = (size_t)b * MLSLOTS_PER_B + pofs + c + s;
#pragma unroll
      for (int mt = 0; mt < 2; ++mt)
#pragma unroll
        for (int r = 0; r < 4; ++r) {
          int rb = mt * 16 + 4 * g + r;
          ml[mlslot * 64 + rb] = mrun[mt][r];
          ml[mlslot * 64 + 32 + rb] = lrun[mt][r];
        }
    }
  }
}

// ---------------- combine partials (chunks c >= 2) ----------------
__global__ __launch_bounds__(256) void combine_kernel(
    const unsigned short* __restrict__ po, const float* __restrict__ ml,
    float* __restrict__ out)
{
  const int tid = threadIdx.x;
  const int b = blockIdx.x;
  const int c = 2 + (int)blockIdx.y;
  const int nt = (c + 2) >> 1;
  const int tps = (nt + 7) >> 3;
  const int nsl = (nt + tps - 1) / tps;       // >= 2 for c >= 2
  int pofs = 0;
  for (int cc = 0; cc < c; ++cc) {
    int ntc = (cc + 2) >> 1, tpsc = (ntc + 7) >> 3;
    pofs += (ntc + tpsc - 1) / tpsc - 1;
  }
  const size_t mlbase = (size_t)b * MLSLOTS_PER_B + pofs + c;
  const size_t pobase = (size_t)b * POSLOTS_PER_B + pofs;

  __shared__ float wgt[32][8];
  if (tid < 32) {
    float M = -1e30f;
    for (int s = 0; s < nsl; ++s)
      M = fmaxf(M, ml[(mlbase + s) * 64 + tid]);
    float L = 0.f;
    for (int s = 0; s < nsl; ++s) {
      float e = __expf(ml[(mlbase + s) * 64 + tid] - M);
      wgt[tid][s] = e;
      L += e * ml[(mlbase + s) * 64 + 32 + tid];
    }
    float invL = 1.f / L;
    for (int s = 0; s < nsl; ++s) wgt[tid][s] *= invL;
  }
  __syncthreads();

#pragma unroll
  for (int it = 0; it < 2; ++it) {
    int vid = it * 256 + tid;                 // 512 = 32 rows x 16 chunks of 8
    int r = vid >> 4, ch = vid & 15;
    float* op = out + ((size_t)b * T_DIM + c * 32 + r) * D_DIM + ch * 8;
    float4 a0 = *(const float4*)op;
    float4 a1 = *(const float4*)(op + 4);
    float w0 = wgt[r][0];
    float o[8] = { w0 * a0.x, w0 * a0.y, w0 * a0.z, w0 * a0.w,
                   w0 * a1.x, w0 * a1.y, w0 * a1.z, w0 * a1.w };
    for (int s = 1; s < nsl; ++s) {
      short8 pv = *(const short8*)(po + (pobase + s - 1) * 4096 + r * 128 + ch * 8);
      float ws = wgt[r][s];
#pragma unroll
      for (int j = 0; j < 8; ++j) o[j] += ws * bf2f((unsigned short)pv[j]);
    }
    *(float4*)op = (float4){o[0], o[1], o[2], o[3]};
    *(float4*)(op + 4) = (float4){o[4], o[5], o[6], o[7]};
  }
}

extern "C" void kernel_launch(void* const* d_in, const int* in_sizes, int n_in,
                              void* d_out, int out_size, void* d_ws, size_t ws_size,
                              hipStream_t stream) {
  const float* q = (const float*)d_in[0];
  const float* k = (const float*)d_in[1];
  const float* v = (const float*)d_in[2];
  // d_in[3] = mask (causal tril, hardcoded)
  const float* mode = (const float*)d_in[4];
  float* out = (float*)d_out;

  char* ws = (char*)d_ws;
  unsigned short* kbf = (unsigned short*)(ws);                 //  4,194,304
  unsigned short* vtb = (unsigned short*)(ws + 4194304);       //  4,194,304
  unsigned short* po  = (unsigned short*)(ws + 8388608);       //  2768 slots * 8192 = 22,675,456
  float*          ml  = (float*)(ws + 31064064);               //  3280 slots * 256  =    839,680
  // total 31,903,744 B  (<= 32,047,104 confirmed available in R2/R3)

  prep_kv<<<dim3(B_DIM, T_DIM / 64), 256, 0, stream>>>(k, v, kbf, vtb);
  attn_kernel<<<dim3(B_DIM, 64, 2), 256, 0, stream>>>(q, kbf, vtb, mode, out, po, ml);
  combine_kernel<<<dim3(B_DIM, 62), 256, 0, stream>>>(po, ml, out);
}

// Round 8
// 61.614 us; speedup vs baseline: 3.1517x; 3.1517x over previous
//
#include <hip/hip_runtime.h>
#include <hip/hip_bf16.h>
#include <cstdint>
#include <cstddef>

// B=8, T=2048, D=128 causal dual-mode attention.
// logits = Qeff . K^T with Qeff[t][d] = -alpha*scale*q[t][d] + (1-alpha)*scale*q[t][(d+1)%D]
// (feature-roll moved from K onto Q), then causal softmax, then @V.
//
// R8: 4-wave (256t) blocks, 128 q-rows (32/wave), KVBLK=64 double-buffered in
// 72KB LDS (2 blocks/CU), segt=4 -> 576 live blocks (~9 waves/CU). Softmax:
// defer-max (T13, THR=8) + epilogue-deferred sum reduction (no per-tile shfl
// chains on the common path). Split-KV: seg0 f32 partial in out, s>=1 bf16 po.

typedef __attribute__((ext_vector_type(8))) short short8;
typedef __attribute__((ext_vector_type(4))) float f32x4;

#define T_DIM 2048
#define D_DIM 128
#define B_DIM 8
#define SEGT 4
#define POSLOTS_PER_B 56    // sum over c=0..15 of (nseg(c)-1), nseg=(c+2)>>1
#define MLSLOTS_PER_B 72    // sum of nseg(c) = 56 + 16

__device__ __forceinline__ unsigned short f2bf(float f) {
  unsigned u = __builtin_bit_cast(unsigned, f);
  u += 0x7FFFu + ((u >> 16) & 1u);          // RNE
  return (unsigned short)(u >> 16);
}
__device__ __forceinline__ float bf2f(unsigned short u) {
  return __uint_as_float(((unsigned)u) << 16);
}
__device__ __forceinline__ void gload_lds16(const void* g, void* l) {
  __builtin_amdgcn_global_load_lds(
      (const __attribute__((address_space(1))) unsigned int*)g,
      (__attribute__((address_space(3))) unsigned int*)l, 16, 0, 0);
}

// ---------------- fused prepass: K->bf16, Qeff->bf16, V->bf16 transposed ----------------
__global__ __launch_bounds__(256) void prep_all(
    const float* __restrict__ q, const float* __restrict__ k, const float* __restrict__ v,
    const float* __restrict__ modep,
    unsigned short* __restrict__ qbf, unsigned short* __restrict__ kbf,
    unsigned short* __restrict__ vt)
{
  __shared__ unsigned short tile[64 * 136];   // V rows as bf16, pitch 136 shorts
  const int b = blockIdx.x, s0 = blockIdx.y * 64;
  const int tid = threadIdx.x;
  const float alpha = 1.f / (1.f + __expf(-modep[0]));
  const float scale = 0.08838834764831845f;
  const float ca = -alpha * scale, cb = (1.f - alpha) * scale;

#pragma unroll
  for (int u = 0; u < 4; ++u) {
    int c = u * 256 + tid;                    // 1024 chunks = 64 rows x 16
    int r = c >> 4, c8 = c & 15;
    size_t row = (size_t)b * T_DIM + s0 + r;
    float4 ka = *(const float4*)(k + row * D_DIM + c8 * 8);
    float4 kb2 = *(const float4*)(k + row * D_DIM + c8 * 8 + 4);
    short8 ko = { (short)f2bf(ka.x), (short)f2bf(ka.y), (short)f2bf(ka.z), (short)f2bf(ka.w),
                  (short)f2bf(kb2.x), (short)f2bf(kb2.y), (short)f2bf(kb2.z), (short)f2bf(kb2.w) };
    *(short8*)(kbf + row * D_DIM + c8 * 8) = ko;
    const float* qr = q + row * D_DIM;
    float e[9];
    float4 f0 = *(const float4*)(qr + c8 * 8);
    float4 f1 = *(const float4*)(qr + c8 * 8 + 4);
    e[0] = f0.x; e[1] = f0.y; e[2] = f0.z; e[3] = f0.w;
    e[4] = f1.x; e[5] = f1.y; e[6] = f1.z; e[7] = f1.w;
    e[8] = qr[(c8 * 8 + 8) & 127];
    short8 qo;
#pragma unroll
    for (int j = 0; j < 8; ++j) qo[j] = (short)f2bf(ca * e[j] + cb * e[j + 1]);
    *(short8*)(qbf + row * D_DIM + c8 * 8) = qo;
    float4 va = *(const float4*)(v + row * D_DIM + c8 * 8);
    float4 vb2 = *(const float4*)(v + row * D_DIM + c8 * 8 + 4);
    short8 vo = { (short)f2bf(va.x), (short)f2bf(va.y), (short)f2bf(va.z), (short)f2bf(va.w),
                  (short)f2bf(vb2.x), (short)f2bf(vb2.y), (short)f2bf(vb2.z), (short)f2bf(vb2.w) };
    *(short8*)(tile + r * 136 + c8 * 8) = vo;
  }
  __syncthreads();
#pragma unroll
  for (int u = 0; u < 8; ++u) {
    int c = u * 256 + tid;                    // 2048 = 128 d x 16 s-quads
    int d = c >> 4, sq = c & 15;
    ushort4 o = { tile[(sq * 4 + 0) * 136 + d], tile[(sq * 4 + 1) * 136 + d],
                  tile[(sq * 4 + 2) * 136 + d], tile[(sq * 4 + 3) * 136 + d] };
    *(ushort4*)(vt + ((size_t)b * D_DIM + d) * T_DIM + s0 + sq * 4) = o;
  }
}

// ---------------- main attention ----------------
// LDS 72KB: K dbuf 2x16KB | V dbuf 2x16KB | P per-wave 4x2KB
__global__ __launch_bounds__(256, 2) void attn_kernel(
    const unsigned short* __restrict__ qbf, const unsigned short* __restrict__ kbf,
    const unsigned short* __restrict__ vt, float* __restrict__ out,
    unsigned short* __restrict__ po, float* __restrict__ ml)
{
  __shared__ uint4 smem4[4608];               // 72 KB
  char* smem = (char*)smem4;
  const int tid = threadIdx.x;
  const int w = tid >> 6, lane = tid & 63;
  const int t16 = lane & 15, g = lane >> 4;
  const int b = blockIdx.x;                   // linear%8==b -> batch pinned to XCD
  const int c = blockIdx.y;                   // 128-row q-chunk (0..15)
  const int s = blockIdx.z;                   // segment (0..7)
  const int nt = 2 * c + 2;                   // causal 64-col tiles for this chunk
  const int nseg = (c + 2) >> 1;              // ceil(nt/SEGT)
  if (s >= nseg) return;
  const int t0 = s * SEGT;
  const int t1 = min(nt, t0 + SEGT);
  const int qb = c * 128 + w * 32;            // wave's first q-row

  char* pw = smem + 65536 + w * 2048;         // per-wave P [16][128B] swizzled
  const unsigned short* kbase = kbf + (size_t)b * T_DIM * D_DIM;
  const unsigned short* vbase = vt + (size_t)b * D_DIM * T_DIM;

  // ---- Qeff fragments (A-layout: row=t16, k=dd*32+g*8+i) ----
  short8 qf[2][4];
#pragma unroll
  for (int mt = 0; mt < 2; ++mt) {
    const unsigned short* qr = qbf + ((size_t)b * T_DIM + qb + mt * 16 + t16) * D_DIM + g * 8;
#pragma unroll
    for (int dd = 0; dd < 4; ++dd) qf[mt][dd] = *(const short8*)(qr + dd * 32);
  }

  f32x4 acc[2][8];
#pragma unroll
  for (int mt = 0; mt < 2; ++mt)
#pragma unroll
    for (int dt = 0; dt < 8; ++dt) acc[mt][dt] = (f32x4){0.f, 0.f, 0.f, 0.f};
  float mrun[2][4], lsum[2][4];
#pragma unroll
  for (int mt = 0; mt < 2; ++mt)
#pragma unroll
    for (int r = 0; r < 4; ++r) { mrun[mt][r] = -1e30f; lsum[mt][r] = 0.f; }

  // ---- staging: wave w does its quarter of K(16KB) and V(16KB) ----
  auto stage = [&](int cur, int kt) {
    const int kv0 = kt * 64;
    char* kb = smem + cur * 16384;
    char* vb = smem + 32768 + cur * 16384;
#pragma unroll
    for (int u = 0; u < 4; ++u) {             // K rows w*16 .. +15
      int s_loc = w * 16 + u * 4 + (lane >> 4);
      int slot = (lane & 15) ^ (s_loc & 7);
      gload_lds16(kbase + (size_t)(kv0 + s_loc) * D_DIM + slot * 8,
                  kb + w * 4096 + u * 1024);
    }
#pragma unroll
    for (int u = 0; u < 4; ++u) {             // V d-rows w*32 .. +31
      int d_loc = w * 32 + u * 8 + (lane >> 3);
      int vslot = (lane & 7) ^ (d_loc & 7);
      gload_lds16(vbase + (size_t)d_loc * T_DIM + kv0 + vslot * 8,
                  vb + w * 4096 + u * 1024);
    }
  };

  stage(0, t0);
  __syncthreads();                            // drain first tile
  int cur = 0;

  for (int kt = t0; kt < t1; ++kt) {
    if (kt + 1 < t1) stage(cur ^ 1, kt + 1);  // prefetch overlaps compute
    const int kv0 = kt * 64;

    if (kv0 <= qb + 31) {                     // wave-causal: skip beyond-diagonal tiles
      char* kb = smem + cur * 16384;
      char* vb = smem + 32768 + cur * 16384;

      // ---- S = Qeff . K^T ----
      f32x4 sj[2][4];
#pragma unroll
      for (int jt = 0; jt < 4; ++jt) {
        int srow = jt * 16 + t16;
        int rb = srow * 256, swz = (srow & 7) << 4;
        f32x4 s0 = (f32x4){0.f, 0.f, 0.f, 0.f};
        f32x4 s1 = (f32x4){0.f, 0.f, 0.f, 0.f};
#pragma unroll
        for (int dd = 0; dd < 4; ++dd) {
          short8 kf = *(const short8*)(kb + ((rb + dd * 64 + g * 16) ^ swz));
          s0 = __builtin_amdgcn_mfma_f32_16x16x32_bf16(qf[0][dd], kf, s0, 0, 0, 0);
          s1 = __builtin_amdgcn_mfma_f32_16x16x32_bf16(qf[1][dd], kf, s1, 0, 0, 0);
        }
        sj[0][jt] = s0; sj[1][jt] = s1;
      }

      // ---- causal mask (only diagonal tiles) ----
      if (kv0 + 63 > qb) {
#pragma unroll
        for (int mt = 0; mt < 2; ++mt)
#pragma unroll
          for (int jt = 0; jt < 4; ++jt) {
            int sg = kv0 + jt * 16 + t16;
#pragma unroll
            for (int r = 0; r < 4; ++r) {
              int tg = qb + mt * 16 + 4 * g + r;
              if (sg > tg) sj[mt][jt][r] = -1e30f;
            }
          }
      }

      // ---- defer-max online softmax ----
      float lm[2][4];
      int ok = 1;
#pragma unroll
      for (int mt = 0; mt < 2; ++mt)
#pragma unroll
        for (int r = 0; r < 4; ++r) {
          lm[mt][r] = fmaxf(fmaxf(sj[mt][0][r], sj[mt][1][r]),
                            fmaxf(sj[mt][2][r], sj[mt][3][r]));
          ok &= (lm[mt][r] <= mrun[mt][r] + 8.0f);
        }
      if (!__all(ok)) {
        // rare path: full row-max via shfl chain, rescale acc & lsum
#pragma unroll
        for (int mt = 0; mt < 2; ++mt) {
          float tm[4];
#pragma unroll
          for (int r = 0; r < 4; ++r) tm[r] = lm[mt][r];
#pragma unroll
          for (int r = 0; r < 4; ++r) {
            tm[r] = fmaxf(tm[r], __shfl_xor(tm[r], 1));
            tm[r] = fmaxf(tm[r], __shfl_xor(tm[r], 2));
            tm[r] = fmaxf(tm[r], __shfl_xor(tm[r], 4));
            tm[r] = fmaxf(tm[r], __shfl_xor(tm[r], 8));
          }
#pragma unroll
          for (int r = 0; r < 4; ++r) {
            float mnew = fmaxf(mrun[mt][r], tm[r]);
            float corr = __expf(mrun[mt][r] - mnew);
            mrun[mt][r] = mnew;
            lsum[mt][r] *= corr;
#pragma unroll
            for (int dt = 0; dt < 8; ++dt) acc[mt][dt][r] *= corr;
          }
        }
      }

      // ---- P = exp(S - m), per-lane partial sums, P->LDS, PV ----
#pragma unroll
      for (int mt = 0; mt < 2; ++mt) {
        float ls[4] = {0.f, 0.f, 0.f, 0.f};
#pragma unroll
        for (int jt = 0; jt < 4; ++jt)
#pragma unroll
          for (int r = 0; r < 4; ++r) {
            float p = __expf(sj[mt][jt][r] - mrun[mt][r]);
            sj[mt][jt][r] = p;
            ls[r] += p;
          }
#pragma unroll
        for (int r = 0; r < 4; ++r) lsum[mt][r] += ls[r];
        // P -> per-wave LDS (C-layout -> [row][col] swizzled); intra-wave only
#pragma unroll
        for (int jt = 0; jt < 4; ++jt)
#pragma unroll
          for (int r = 0; r < 4; ++r) {
            int rloc = 4 * g + r;
            *(unsigned short*)(pw + rloc * 128 + ((2 * (jt * 16 + t16)) ^ ((rloc & 7) << 4))) =
                f2bf(sj[mt][jt][r]);
          }
        // O[mt] += P . V
#pragma unroll
        for (int k0 = 0; k0 < 2; ++k0) {
          short8 pf = *(const short8*)(pw + t16 * 128 + ((k0 * 64 + g * 16) ^ ((t16 & 7) << 4)));
#pragma unroll
          for (int dt = 0; dt < 8; ++dt) {
            int d = dt * 16 + t16;
            short8 vf = *(const short8*)(vb + d * 128 + (((k0 * 4 + g) << 4) ^ ((d & 7) << 4)));
            acc[mt][dt] = __builtin_amdgcn_mfma_f32_16x16x32_bf16(pf, vf, acc[mt][dt], 0, 0, 0);
          }
        }
      }
    }

    __syncthreads();                          // drain prefetch + finish reads of cur
    cur ^= 1;
  }

  // ---- deferred row-sum reduction (once per kernel) ----
  float lred[2][4];
#pragma unroll
  for (int mt = 0; mt < 2; ++mt)
#pragma unroll
    for (int r = 0; r < 4; ++r) {
      float v0 = lsum[mt][r];
      v0 += __shfl_xor(v0, 1);
      v0 += __shfl_xor(v0, 2);
      v0 += __shfl_xor(v0, 4);
      v0 += __shfl_xor(v0, 8);
      lred[mt][r] = v0;
    }

  // ---- epilogue ----
  if (nseg == 1) {
#pragma unroll
    for (int mt = 0; mt < 2; ++mt)
#pragma unroll
      for (int r = 0; r < 4; ++r) {
        float inv = 1.0f / lred[mt][r];
#pragma unroll
        for (int dt = 0; dt < 8; ++dt)
          out[((size_t)b * T_DIM + qb + mt * 16 + 4 * g + r) * D_DIM + dt * 16 + t16] =
              acc[mt][dt][r] * inv;
      }
  } else {
    int pofs = 0;                             // sum over cc<c of (nseg(cc)-1)
    for (int cc = 0; cc < c; ++cc) pofs += ((cc + 2) >> 1) - 1;
    if (s == 0) {
      // seg0 partial (unnormalized f32) lives in out[]
#pragma unroll
      for (int mt = 0; mt < 2; ++mt)
#pragma unroll
        for (int r = 0; r < 4; ++r)
#pragma unroll
          for (int dt = 0; dt < 8; ++dt)
            out[((size_t)b * T_DIM + qb + mt * 16 + 4 * g + r) * D_DIM + dt * 16 + t16] =
                acc[mt][dt][r];
    } else {
      unsigned short* pob = po + ((size_t)b * POSLOTS_PER_B + pofs + (s - 1)) * 16384;
#pragma unroll
      for (int mt = 0; mt < 2; ++mt)
#pragma unroll
        for (int r = 0; r < 4; ++r) {
          int rb = w * 32 + mt * 16 + 4 * g + r;
#pragma unroll
          for (int dt = 0; dt < 8; ++dt)
            pob[rb * 128 + dt * 16 + t16] = f2bf(acc[mt][dt][r]);
        }
    }
    if (t16 == 0) {
      const size_t mlslot = (size_t)b * MLSLOTS_PER_B + pofs + c + s;
#pragma unroll
      for (int mt = 0; mt < 2; ++mt)
#pragma unroll
        for (int r = 0; r < 4; ++r) {
          int rb = w * 32 + mt * 16 + 4 * g + r;
          ml[mlslot * 256 + rb] = mrun[mt][r];
          ml[mlslot * 256 + 128 + rb] = lred[mt][r];
        }
    }
  }
}

// ---------------- combine partials (chunks c >= 2) ----------------
__global__ __launch_bounds__(256) void combine_kernel(
    const unsigned short* __restrict__ po, const float* __restrict__ ml,
    float* __restrict__ out)
{
  const int tid = threadIdx.x;
  const int b = blockIdx.x;
  const int c = 2 + (int)blockIdx.y;
  const int nseg = (c + 2) >> 1;              // 2..8
  int pofs = 0;
  for (int cc = 0; cc < c; ++cc) pofs += ((cc + 2) >> 1) - 1;
  const size_t mlbase = (size_t)b * MLSLOTS_PER_B + pofs + c;
  const size_t pobase = (size_t)b * POSLOTS_PER_B + pofs;

  __shared__ float wgt[128][8];
  if (tid < 128) {
    float M = -1e30f;
    for (int s = 0; s < nseg; ++s)
      M = fmaxf(M, ml[(mlbase + s) * 256 + tid]);
    float L = 0.f;
    for (int s = 0; s < nseg; ++s) {
      float e = __expf(ml[(mlbase + s) * 256 + tid] - M);
      wgt[tid][s] = e;
      L += e * ml[(mlbase + s) * 256 + 128 + tid];
    }
    float invL = 1.f / L;
    for (int s = 0; s < nseg; ++s) wgt[tid][s] *= invL;
  }
  __syncthreads();

#pragma unroll
  for (int it = 0; it < 8; ++it) {
    int vid = it * 256 + tid;                 // 2048 = 128 rows x 16 chunks of 8
    int r = vid >> 4, ch = vid & 15;
    float* op = out + ((size_t)b * T_DIM + c * 128 + r) * D_DIM + ch * 8;
    float4 a0 = *(const float4*)op;
    float4 a1 = *(const float4*)(op + 4);
    float w0 = wgt[r][0];
    float o[8] = { w0 * a0.x, w0 * a0.y, w0 * a0.z, w0 * a0.w,
                   w0 * a1.x, w0 * a1.y, w0 * a1.z, w0 * a1.w };
    for (int s = 1; s < nseg; ++s) {
      short8 pv = *(const short8*)(po + (pobase + s - 1) * 16384 + r * 128 + ch * 8);
      float ws = wgt[r][s];
#pragma unroll
      for (int j = 0; j < 8; ++j) o[j] += ws * bf2f((unsigned short)pv[j]);
    }
    *(float4*)op = (float4){o[0], o[1], o[2], o[3]};
    *(float4*)(op + 4) = (float4){o[4], o[5], o[6], o[7]};
  }
}

extern "C" void kernel_launch(void* const* d_in, const int* in_sizes, int n_in,
                              void* d_out, int out_size, void* d_ws, size_t ws_size,
                              hipStream_t stream) {
  const float* q = (const float*)d_in[0];
  const float* k = (const float*)d_in[1];
  const float* v = (const float*)d_in[2];
  // d_in[3] = mask (causal tril, hardcoded)
  const float* mode = (const float*)d_in[4];
  float* out = (float*)d_out;

  char* ws = (char*)d_ws;
  unsigned short* qbf = (unsigned short*)(ws);                 //  4,194,304
  unsigned short* kbf = (unsigned short*)(ws + 4194304);       //  4,194,304
  unsigned short* vtb = (unsigned short*)(ws + 8388608);       //  4,194,304
  unsigned short* po  = (unsigned short*)(ws + 12582912);      //  56*8 slots * 32KB = 14,680,064
  float*          ml  = (float*)(ws + 27262976);               //  72*8 slots * 1KB  =    589,824
  // total 27,852,800 B (<= 32,047,104 confirmed available)

  prep_all<<<dim3(B_DIM, T_DIM / 64), 256, 0, stream>>>(q, k, v, mode, qbf, kbf, vtb);
  attn_kernel<<<dim3(B_DIM, 16, 8), 256, 0, stream>>>(qbf, kbf, vtb, out, po, ml);
  combine_kernel<<<dim3(B_DIM, 14), 256, 0, stream>>>(po, ml, out);
}